// Round 12
// baseline (247.710 us; speedup 1.0000x reference)
//
#include <hip/hip_runtime.h>

#define T_STEPS 512
#define BATCH   2048
#define HID     64
#define IN0     8
#define SPW     16                // seqs per block (MFMA N dim)
#define NBLK    (BATCH / SPW)     // 128 blocks x 4 waves (256 thr)
#define SS      8                 // x-prefetch depth
#define NSS     (T_STEPS / SS)

typedef _Float16 h2 __attribute__((ext_vector_type(2)));
typedef _Float16 h8 __attribute__((ext_vector_type(8)));
typedef float    f4 __attribute__((ext_vector_type(4)));
typedef float    f2 __attribute__((ext_vector_type(2)));

#define MFMA(a, b, c) __builtin_amdgcn_mfma_f32_16x16x32_f16((a), (b), (c), 0, 0, 0)

union F8 { h8 v; h2 p[4]; };

__device__ __forceinline__ h2 pkrtz(float a, float b) {
    return __builtin_bit_cast(h2, __builtin_amdgcn_cvt_pkrtz(a, b));
}

// ---- packed-f32 ops (CDNA dual-FP32: 2 elems/instr at scalar issue cost) ----
__device__ __forceinline__ f2 pk_fma(f2 a, f2 b, f2 c) {
    f2 d;
    asm("v_pk_fma_f32 %0, %1, %2, %3" : "=v"(d) : "v"(a), "v"(b), "v"(c));
    return d;
}
__device__ __forceinline__ f2 pk_mul(f2 a, f2 b) {
    f2 d;
    asm("v_pk_mul_f32 %0, %1, %2" : "=v"(d) : "v"(a), "v"(b));
    return d;
}
__device__ __forceinline__ f2 pk_add(f2 a, f2 b) {
    f2 d;
    asm("v_pk_add_f32 %0, %1, %2" : "=v"(d) : "v"(a), "v"(b));
    return d;
}

// tanh via Pade(7,6): x(10395+1260y+21y^2)/(10395+4725y+210y^2+y^3), y=x^2,
// clamp |x|<=4.5. Max err ~3.7e-4 in-range, ~6.2e-4 saturated tail (~1 f16
// ulp; f16 storage rounding is 4.9e-4). 1 trans + ~15 VALU per PAIR vs the
// exp-based version's 4 trans + 6 VALU (trans = ~16cy issue; measured R10:
// trans was 77% of all VALU issue and sits on the critical chain).
__device__ __forceinline__ h2 tanh2_pk(float xa, float xb) {
    const f2 C21    = {21.f, 21.f};
    const f2 C1260  = {1260.f, 1260.f};
    const f2 C10395 = {10395.f, 10395.f};
    const f2 C210   = {210.f, 210.f};
    const f2 C4725  = {4725.f, 4725.f};
    f2 c;
    c[0] = __builtin_amdgcn_fmed3f(xa, -4.5f, 4.5f);
    c[1] = __builtin_amdgcn_fmed3f(xb, -4.5f, 4.5f);
    const f2 y = pk_mul(c, c);
    f2 n = pk_fma(y, C21, C1260);
    n = pk_fma(y, n, C10395);
    n = pk_mul(n, c);
    f2 d = pk_add(y, C210);
    d = pk_fma(y, d, C4725);
    d = pk_fma(y, d, C10395);
    const float r = __builtin_amdgcn_rcpf(d[0] * d[1]);   // shared rcp
    const float tx = n[0] * (r * d[1]);
    const float ty = n[1] * (r * d[0]);
    return pkrtz(tx, ty);
}

// scalar tanh for the one-off epilogue
__device__ __forceinline__ float tanh_fast(float x) {
    float e = __builtin_amdgcn_exp2f(x * 2.885390081777927f);
    return 1.0f - 2.0f * __builtin_amdgcn_rcpf(e + 1.0f);
}

__device__ __forceinline__ h8 load_frag_f16(const float* Wrow) {
    const float4* p = (const float4*)Wrow;
    float4 a = p[0], b = p[1];
    F8 f; f.p[0] = pkrtz(a.x, a.y); f.p[1] = pkrtz(a.z, a.w);
          f.p[2] = pkrtz(b.x, b.y); f.p[3] = pkrtz(b.z, b.w);
    return f.v;
}

// Barrier draining ONLY lgkmcnt (LDS); x-prefetch globals stay in flight.
// lgkmcnt(0) also retires this step's stable-buffer READS before any wave
// can cross and overwrite them next step (double-buffer race-safety).
#define LDS_BARRIER() asm volatile("s_waitcnt lgkmcnt(0)\n\ts_barrier" ::: "memory")

// sigma row permutation (verified R2/R9): C slot (mt, 4q+r) holds actual H
// row 32*(mt>>1) + 4*(mt&1) + 8*q + r, so a wave owning m-tiles {2hf,2hf+1}
// packs its 8 C values into the COMPLETE k-tile-hf B operand. Exchange =
// 1 ds_write_b128 + 1 ds_read_b128 per step (conflict-free, measured R9).
__global__ __launch_bounds__(256, 1)
void rnn2_rat(const float* __restrict__ x,
              const float* __restrict__ Wih0, const float* __restrict__ Whh0,
              const float* __restrict__ bih0, const float* __restrict__ bhh0,
              const float* __restrict__ Wih1, const float* __restrict__ Whh1,
              const float* __restrict__ bih1, const float* __restrict__ bhh1,
              const float* __restrict__ fcw,  const float* __restrict__ fcb,
              float* __restrict__ out) {
    const int tid  = threadIdx.x;
    const int w    = tid >> 6;     // 0,1 = L0 halves; 2,3 = L1 halves
    const int lane = tid & 63;
    const int n    = lane & 15;    // seq column / A-row-slot
    const int q    = lane >> 4;
    const int bseq = blockIdx.x * SPW;
    const bool isL0 = (w < 2);
    const int hf   = isL0 ? w : (w - 2);   // owned k-tile
    const int mt0  = 2 * hf;               // owned m-tiles: mt0, mt0+1

    // [bf][half][lane] complete B-fragments; 16B/lane linear (0 conflicts,
    // measured R9). 8.2 KB total.
    __shared__ __align__(16) h8 X0[2][2][64];
    __shared__ __align__(16) h8 X1[2][2][64];
    __shared__ float red[2][SPW];

    // zero-init: H0(-1)=H1(-1)=0 reads at t=0/1 come from these
    {
        h8 z = {};
        X0[w >> 1][w & 1][lane] = z;
        X1[w >> 1][w & 1][lane] = z;
    }
    __syncthreads();

    const f4 zero = {0.f, 0.f, 0.f, 0.f};
    const h2 z2 = pkrtz(0.f, 0.f);
    const float fcb0 = fcb[0];

    if (isL0) {
        // ---------------- layer-0 half-wave ----------------
        h8 wh[2][2], wi[2];        // [l][kt]; l: local m-tile
        f4 bias[2];
        #pragma unroll
        for (int l = 0; l < 2; ++l) {
            const int mt = mt0 + l;
            const int ar = 32 * (mt >> 1) + 4 * (mt & 1) + 8 * (n >> 2) + (n & 3);
            #pragma unroll
            for (int kt = 0; kt < 2; ++kt)
                wh[l][kt] = load_frag_f16(Whh0 + ar * HID + 32 * kt + 8 * q);
            const float2 ww = *(const float2*)(Wih0 + ar * IN0 + 2 * q);
            F8 f; f.p[0] = pkrtz(ww.x, ww.y); f.p[1] = z2; f.p[2] = z2; f.p[3] = z2;
            wi[l] = f.v;
            #pragma unroll
            for (int r = 0; r < 4; ++r) {
                const int cr = 32 * (mt >> 1) + 4 * (mt & 1) + 8 * q + r;
                bias[l][r] = bih0[cr] + bhh0[cr];
            }
        }
        const float* xrow = x + ((size_t)(bseq + n)) * T_STEPS * IN0 + 2 * q;
        float2 xb[SS];             // xb[t&7] = x(t) at top of step t
        #pragma unroll
        for (int i = 0; i < SS; ++i)
            xb[i] = *(const float2*)(xrow + i * IN0);

        h8 own = {};               // own half of H0(t-1); H0(-1)=0
        for (int s = 0; s < NSS; ++s) {
            #pragma unroll
            for (int i = 0; i < SS; ++i) {
                const int t = SS * s + i;
                const int bf = t & 1;
                // (1) chain read FIRST: sibling half of H0(t-1)
                const h8 other = X0[bf ^ 1][hf ^ 1][lane];
                // (2) read shadow: cpart(t) = bias + Wih@x(t) + Whh[own]@own(t-1)
                F8 xf; xf.p[0] = pkrtz(xb[i].x, xb[i].y);
                xf.p[1] = z2; xf.p[2] = z2; xf.p[3] = z2;
                f4 cp0 = MFMA(wi[0], xf.v, bias[0]);
                f4 cp1 = MFMA(wi[1], xf.v, bias[1]);
                cp0 = MFMA(wh[0][hf], own, cp0);
                cp1 = MFMA(wh[1][hf], own, cp1);
                // x refill (lands in 8 steps; off-chain issue)
                int tn = t + SS; if (tn > T_STEPS - 1) tn = T_STEPS - 1;
                xb[i] = *(const float2*)(xrow + tn * IN0);
                // (3) chain: finish MFMA, rational tanh, pack, publish
                f4 c0 = MFMA(wh[0][hf ^ 1], other, cp0);
                f4 c1 = MFMA(wh[1][hf ^ 1], other, cp1);
                F8 pk;
                pk.p[0] = tanh2_pk(c0[0], c0[1]);
                pk.p[1] = tanh2_pk(c0[2], c0[3]);
                pk.p[2] = tanh2_pk(c1[0], c1[1]);
                pk.p[3] = tanh2_pk(c1[2], c1[3]);
                own = pk.v;                    // full k-tile-hf B-frag of H0(t)
                X0[bf][hf][lane] = own;
                LDS_BARRIER();
            }
        }
    } else {
        // ---------------- layer-1 half-wave ----------------
        // step t computes H1(t-1); ALL inputs are stable bf^1 buffers.
        h8 wa[2][2], wb[2][2];
        f4 bias[2], fcv[2];
        #pragma unroll
        for (int l = 0; l < 2; ++l) {
            const int mt = mt0 + l;
            const int ar = 32 * (mt >> 1) + 4 * (mt & 1) + 8 * (n >> 2) + (n & 3);
            #pragma unroll
            for (int kt = 0; kt < 2; ++kt) {
                wa[l][kt] = load_frag_f16(Wih1 + ar * HID + 32 * kt + 8 * q);
                wb[l][kt] = load_frag_f16(Whh1 + ar * HID + 32 * kt + 8 * q);
            }
            #pragma unroll
            for (int r = 0; r < 4; ++r) {
                const int cr = 32 * (mt >> 1) + 4 * (mt & 1) + 8 * q + r;
                bias[l][r] = bih1[cr] + bhh1[cr];
                fcv[l][r]  = fcw[cr];
            }
        }
        h8 own1 = {};              // own H1 half (t-2 at step top); H1(-1)=0
        for (int s = 0; s < NSS; ++s) {
            #pragma unroll
            for (int i = 0; i < SS; ++i) {
                const int t = SS * s + i;
                const int bf = t & 1;
                // (1) chain reads FIRST
                const h8 h00 = X0[bf ^ 1][0][lane];      // H0(t-1) both halves
                const h8 h01 = X0[bf ^ 1][1][lane];
                const h8 h1o = X1[bf ^ 1][hf ^ 1][lane]; // sibling H1(t-2)
                // (2) read shadow: own-half H1 partials (own1 in registers)
                f4 g0 = MFMA(wb[0][hf], own1, zero);
                f4 g1 = MFMA(wb[1][hf], own1, zero);
                // (3) chain when reads land
                f4 e0 = MFMA(wa[0][0], h00, bias[0]);
                f4 e1 = MFMA(wa[1][0], h00, bias[1]);
                e0 = MFMA(wa[0][1], h01, e0);
                e1 = MFMA(wa[1][1], h01, e1);
                g0 = MFMA(wb[0][hf ^ 1], h1o, g0);
                g1 = MFMA(wb[1][hf ^ 1], h1o, g1);
                const f4 d0 = e0 + g0, d1 = e1 + g1;
                F8 pk;
                pk.p[0] = tanh2_pk(d0[0], d0[1]);
                pk.p[1] = tanh2_pk(d0[2], d0[3]);
                pk.p[2] = tanh2_pk(d1[0], d1[1]);
                pk.p[3] = tanh2_pk(d1[2], d1[3]);
                h8 newown = pk.v;
                if (t == 0) { h8 z = {}; newown = z; }    // true H1(-1)=0
                own1 = newown;
                X1[bf][hf][lane] = own1;
                LDS_BARRIER();
            }
        }
        // epilogue: H1(511) from H0(511)=X0[1], H1(510)={own1, X1[1][hf^1]}
        {
            const h8 h00 = X0[1][0][lane];
            const h8 h01 = X0[1][1][lane];
            const h8 h1o = X1[1][hf ^ 1][lane];
            f4 e0 = MFMA(wa[0][0], h00, bias[0]);
            e0    = MFMA(wa[0][1], h01, e0);
            f4 g0 = MFMA(wb[0][hf ^ 1], h1o, zero);
            g0    = MFMA(wb[0][hf], own1, g0);
            f4 e1 = MFMA(wa[1][0], h00, bias[1]);
            e1    = MFMA(wa[1][1], h01, e1);
            f4 g1 = MFMA(wb[1][hf ^ 1], h1o, zero);
            g1    = MFMA(wb[1][hf], own1, g1);
            const f4 d0 = e0 + g0, d1 = e1 + g1;
            float sacc = 0.f;
            #pragma unroll
            for (int r = 0; r < 4; ++r) {
                sacc += fcv[0][r] * tanh_fast(d0[r]);
                sacc += fcv[1][r] * tanh_fast(d1[r]);
            }
            sacc += __shfl_xor(sacc, 16, 64);
            sacc += __shfl_xor(sacc, 32, 64);
            if (lane < 16) red[hf][n] = sacc;   // q==0 lanes
        }
    }

    __syncthreads();
    if (tid < SPW)
        out[bseq + tid] = red[0][tid] + red[1][tid] + fcb0;
}

extern "C" void kernel_launch(void* const* d_in, const int* in_sizes, int n_in,
                              void* d_out, int out_size, void* d_ws, size_t ws_size,
                              hipStream_t stream) {
    const float* x    = (const float*)d_in[0];
    const float* Wih0 = (const float*)d_in[1];
    const float* Whh0 = (const float*)d_in[2];
    const float* bih0 = (const float*)d_in[3];
    const float* bhh0 = (const float*)d_in[4];
    const float* Wih1 = (const float*)d_in[5];
    const float* Whh1 = (const float*)d_in[6];
    const float* bih1 = (const float*)d_in[7];
    const float* bhh1 = (const float*)d_in[8];
    const float* fcw  = (const float*)d_in[9];
    const float* fcb  = (const float*)d_in[10];
    float* out = (float*)d_out;

    rnn2_rat<<<dim3(NBLK), dim3(256), 0, stream>>>(
        x, Wih0, Whh0, bih0, bhh0, Wih1, Whh1, bih1, bhh1, fcw, fcb, out);
}

// Round 13
// 223.856 us; speedup vs baseline: 1.1066x; 1.1066x over previous
//
#include <hip/hip_runtime.h>

#define T_STEPS 512
#define BATCH   2048
#define HID     64
#define IN0     8
#define SPW     16                // seqs per block (MFMA N dim)
#define NBLK    (BATCH / SPW)     // 128 blocks x 4 waves (256 thr)
#define SS      8                 // x-prefetch depth
#define NSS     (T_STEPS / SS)

// 2*log2(e): folded into all weights/biases so tanh needs no input scaling
#define KSC 2.885390081777927f

typedef _Float16 h2 __attribute__((ext_vector_type(2)));
typedef _Float16 h8 __attribute__((ext_vector_type(8)));
typedef float    f4 __attribute__((ext_vector_type(4)));

#define MFMA(a, b, c) __builtin_amdgcn_mfma_f32_16x16x32_f16((a), (b), (c), 0, 0, 0)

union F8 { h8 v; h2 p[4]; };

__device__ __forceinline__ h2 pkrtz(float a, float b) {
    return __builtin_bit_cast(h2, __builtin_amdgcn_cvt_pkrtz(a, b));
}

// tanh(a) where input kx = KSC*a (pre-scaled via weights):
// 4 instrs/elem (exp2, add, rcp, fma); saturates correctly at +/-inf.
__device__ __forceinline__ float tanh_pre(float kx) {
    float e = __builtin_amdgcn_exp2f(kx);
    return 1.0f - 2.0f * __builtin_amdgcn_rcpf(e + 1.0f);
}

// fragment load with fold-in scale (runs once at init; cost irrelevant)
__device__ __forceinline__ h8 load_frag_f16_s(const float* Wrow, float s) {
    const float4* p = (const float4*)Wrow;
    float4 a = p[0], b = p[1];
    F8 f; f.p[0] = pkrtz(s * a.x, s * a.y); f.p[1] = pkrtz(s * a.z, s * a.w);
          f.p[2] = pkrtz(s * b.x, s * b.y); f.p[3] = pkrtz(s * b.z, s * b.w);
    return f.v;
}

// Barrier draining ONLY lgkmcnt (LDS); x-prefetch globals stay in flight.
// lgkmcnt(0) also retires this step's stable-buffer READS before any wave
// can cross and overwrite them next step (double-buffer race-safety).
#define LDS_BARRIER() asm volatile("s_waitcnt lgkmcnt(0)\n\ts_barrier" ::: "memory")

// sigma row permutation (verified R2/R9): C slot (mt, 4q+r) holds actual H
// row 32*(mt>>1) + 4*(mt&1) + 8*q + r, so a wave owning m-tiles {2hf,2hf+1}
// packs its 8 C values into the COMPLETE k-tile-hf B operand. Exchange =
// 1 ds_write_b128 + 1 ds_read_b128 per step (conflict-free, measured R9).
// HW model (fit R2/R3/R10/R11): lone wave issues ~6cy/instr -> minimize
// instruction count on the critical waves.
__global__ __launch_bounds__(256, 1)
void rnn2_k4(const float* __restrict__ x,
             const float* __restrict__ Wih0, const float* __restrict__ Whh0,
             const float* __restrict__ bih0, const float* __restrict__ bhh0,
             const float* __restrict__ Wih1, const float* __restrict__ Whh1,
             const float* __restrict__ bih1, const float* __restrict__ bhh1,
             const float* __restrict__ fcw,  const float* __restrict__ fcb,
             float* __restrict__ out) {
    const int tid  = threadIdx.x;
    const int w    = tid >> 6;     // 0,1 = L0 halves; 2,3 = L1 halves
    const int lane = tid & 63;
    const int n    = lane & 15;    // seq column / A-row-slot
    const int q    = lane >> 4;
    const int bseq = blockIdx.x * SPW;
    const bool isL0 = (w < 2);
    const int hf   = isL0 ? w : (w - 2);   // owned k-tile
    const int mt0  = 2 * hf;               // owned m-tiles: mt0, mt0+1

    // [bf][half][lane] complete B-fragments; 16B/lane linear (0 conflicts,
    // measured R9). 8.2 KB total.
    __shared__ __align__(16) h8 X0[2][2][64];
    __shared__ __align__(16) h8 X1[2][2][64];
    __shared__ float red[2][SPW];

    // zero-init: H0(-1)=H1(-1)=0 reads at t=0/1 come from these
    {
        h8 z = {};
        X0[w >> 1][w & 1][lane] = z;
        X1[w >> 1][w & 1][lane] = z;
    }
    __syncthreads();

    const h2 z2 = pkrtz(0.f, 0.f);
    const float fcb0 = fcb[0];

    if (isL0) {
        // ---------------- layer-0 half-wave ----------------
        h8 wh[2][2], wi[2];        // [l][kt]; l: local m-tile (KSC-scaled)
        f4 bias[2];
        #pragma unroll
        for (int l = 0; l < 2; ++l) {
            const int mt = mt0 + l;
            const int ar = 32 * (mt >> 1) + 4 * (mt & 1) + 8 * (n >> 2) + (n & 3);
            #pragma unroll
            for (int kt = 0; kt < 2; ++kt)
                wh[l][kt] = load_frag_f16_s(Whh0 + ar * HID + 32 * kt + 8 * q, KSC);
            const float2 ww = *(const float2*)(Wih0 + ar * IN0 + 2 * q);
            F8 f; f.p[0] = pkrtz(KSC * ww.x, KSC * ww.y);
            f.p[1] = z2; f.p[2] = z2; f.p[3] = z2;
            wi[l] = f.v;
            #pragma unroll
            for (int r = 0; r < 4; ++r) {
                const int cr = 32 * (mt >> 1) + 4 * (mt & 1) + 8 * q + r;
                bias[l][r] = KSC * (bih0[cr] + bhh0[cr]);
            }
        }
        const float* xrow = x + ((size_t)(bseq + n)) * T_STEPS * IN0 + 2 * q;
        float2 xb[SS];             // xb[t&7] = x(t) at top of step t
        #pragma unroll
        for (int i = 0; i < SS; ++i)
            xb[i] = *(const float2*)(xrow + i * IN0);

        h8 own = {};               // own half of H0(t-1); H0(-1)=0
        for (int s = 0; s < NSS; ++s) {
            #pragma unroll
            for (int i = 0; i < SS; ++i) {
                const int t = SS * s + i;
                const int bf = t & 1;
                // (1) chain read FIRST: sibling half of H0(t-1)
                const h8 other = X0[bf ^ 1][hf ^ 1][lane];
                // (2) read shadow: cpart = bias + Wih@x(t) + Whh[own]@own(t-1)
                F8 xf; xf.p[0] = pkrtz(xb[i].x, xb[i].y);
                xf.p[1] = z2; xf.p[2] = z2; xf.p[3] = z2;
                f4 cp0 = MFMA(wi[0], xf.v, bias[0]);
                f4 cp1 = MFMA(wi[1], xf.v, bias[1]);
                cp0 = MFMA(wh[0][hf], own, cp0);
                cp1 = MFMA(wh[1][hf], own, cp1);
                // x refill (lands in 8 steps; off-chain issue)
                int tn = t + SS; if (tn > T_STEPS - 1) tn = T_STEPS - 1;
                xb[i] = *(const float2*)(xrow + tn * IN0);
                // (3) chain: finish MFMA, tanh(4-instr), pack, publish
                f4 c0 = MFMA(wh[0][hf ^ 1], other, cp0);
                f4 c1 = MFMA(wh[1][hf ^ 1], other, cp1);
                F8 pk;
                pk.p[0] = pkrtz(tanh_pre(c0[0]), tanh_pre(c0[1]));
                pk.p[1] = pkrtz(tanh_pre(c0[2]), tanh_pre(c0[3]));
                pk.p[2] = pkrtz(tanh_pre(c1[0]), tanh_pre(c1[1]));
                pk.p[3] = pkrtz(tanh_pre(c1[2]), tanh_pre(c1[3]));
                own = pk.v;                    // full k-tile-hf B-frag of H0(t)
                X0[bf][hf][lane] = own;
                LDS_BARRIER();
            }
        }
    } else {
        // ---------------- layer-1 half-wave ----------------
        // step t computes H1(t-1); ALL inputs are stable bf^1 buffers.
        h8 wa[2][2], wb[2][2];     // KSC-scaled
        f4 bias[2], fcv[2];
        #pragma unroll
        for (int l = 0; l < 2; ++l) {
            const int mt = mt0 + l;
            const int ar = 32 * (mt >> 1) + 4 * (mt & 1) + 8 * (n >> 2) + (n & 3);
            #pragma unroll
            for (int kt = 0; kt < 2; ++kt) {
                wa[l][kt] = load_frag_f16_s(Wih1 + ar * HID + 32 * kt + 8 * q, KSC);
                wb[l][kt] = load_frag_f16_s(Whh1 + ar * HID + 32 * kt + 8 * q, KSC);
            }
            #pragma unroll
            for (int r = 0; r < 4; ++r) {
                const int cr = 32 * (mt >> 1) + 4 * (mt & 1) + 8 * q + r;
                bias[l][r] = KSC * (bih1[cr] + bhh1[cr]);
                fcv[l][r]  = fcw[cr];          // unscaled: applied post-tanh
            }
        }
        h8 own1 = {};              // own H1 half (t-2 at step top); H1(-1)=0
        for (int s = 0; s < NSS; ++s) {
            #pragma unroll
            for (int i = 0; i < SS; ++i) {
                const int t = SS * s + i;
                const int bf = t & 1;
                // (1) chain reads FIRST (stable buffers)
                const h8 h00 = X0[bf ^ 1][0][lane];      // H0(t-1) both halves
                const h8 h01 = X0[bf ^ 1][1][lane];
                const h8 h1o = X1[bf ^ 1][hf ^ 1][lane]; // sibling H1(t-2)
                // (2) read shadow: first MFMA of each chain is pure-register
                f4 e0 = MFMA(wb[0][hf], own1, bias[0]);
                f4 e1 = MFMA(wb[1][hf], own1, bias[1]);
                // (3) fully-chained accumulate (no tree adds, no zero)
                e0 = MFMA(wa[0][0], h00, e0);
                e1 = MFMA(wa[1][0], h00, e1);
                e0 = MFMA(wa[0][1], h01, e0);
                e1 = MFMA(wa[1][1], h01, e1);
                e0 = MFMA(wb[0][hf ^ 1], h1o, e0);
                e1 = MFMA(wb[1][hf ^ 1], h1o, e1);
                F8 pk;
                pk.p[0] = pkrtz(tanh_pre(e0[0]), tanh_pre(e0[1]));
                pk.p[1] = pkrtz(tanh_pre(e0[2]), tanh_pre(e0[3]));
                pk.p[2] = pkrtz(tanh_pre(e1[0]), tanh_pre(e1[1]));
                pk.p[3] = pkrtz(tanh_pre(e1[2]), tanh_pre(e1[3]));
                // t==0 computes H1(-1) which must stay 0: keep init values
                // (uniform branch, exists only in the i==0 unroll body)
                if (i == 0) {
                    if (s != 0) { own1 = pk.v; X1[bf][hf][lane] = own1; }
                } else {
                    own1 = pk.v; X1[bf][hf][lane] = own1;
                }
                LDS_BARRIER();
            }
        }
        // epilogue: H1(511) from H0(511)=X0[1], H1(510)={own1, X1[1][hf^1]}
        {
            const h8 h00 = X0[1][0][lane];
            const h8 h01 = X0[1][1][lane];
            const h8 h1o = X1[1][hf ^ 1][lane];
            f4 e0 = MFMA(wb[0][hf], own1, bias[0]);
            f4 e1 = MFMA(wb[1][hf], own1, bias[1]);
            e0 = MFMA(wa[0][0], h00, e0);
            e1 = MFMA(wa[1][0], h00, e1);
            e0 = MFMA(wa[0][1], h01, e0);
            e1 = MFMA(wa[1][1], h01, e1);
            e0 = MFMA(wb[0][hf ^ 1], h1o, e0);
            e1 = MFMA(wb[1][hf ^ 1], h1o, e1);
            float sacc = 0.f;
            #pragma unroll
            for (int r = 0; r < 4; ++r) {
                sacc += fcv[0][r] * tanh_pre(e0[r]);
                sacc += fcv[1][r] * tanh_pre(e1[r]);
            }
            sacc += __shfl_xor(sacc, 16, 64);
            sacc += __shfl_xor(sacc, 32, 64);
            if (lane < 16) red[hf][n] = sacc;   // q==0 lanes
        }
    }

    __syncthreads();
    if (tid < SPW)
        out[bseq + tid] = red[0][tid] + red[1][tid] + fcb0;
}

extern "C" void kernel_launch(void* const* d_in, const int* in_sizes, int n_in,
                              void* d_out, int out_size, void* d_ws, size_t ws_size,
                              hipStream_t stream) {
    const float* x    = (const float*)d_in[0];
    const float* Wih0 = (const float*)d_in[1];
    const float* Whh0 = (const float*)d_in[2];
    const float* bih0 = (const float*)d_in[3];
    const float* bhh0 = (const float*)d_in[4];
    const float* Wih1 = (const float*)d_in[5];
    const float* Whh1 = (const float*)d_in[6];
    const float* bih1 = (const float*)d_in[7];
    const float* bhh1 = (const float*)d_in[8];
    const float* fcw  = (const float*)d_in[9];
    const float* fcb  = (const float*)d_in[10];
    float* out = (float*)d_out;

    rnn2_k4<<<dim3(NBLK), dim3(256), 0, stream>>>(
        x, Wih0, Whh0, bih0, bhh0, Wih1, Whh1, bih1, bhh1, fcw, fcb, out);
}

// Round 14
// 206.354 us; speedup vs baseline: 1.2004x; 1.0848x over previous
//
#include <hip/hip_runtime.h>

#define T_STEPS 512
#define BATCH   2048
#define HID     64
#define IN0     8
#define SPW     16                // seqs per block (MFMA N dim)
#define NBLK    (BATCH / SPW)     // 128 blocks x 8 waves (512 thr)
#define SS      8                 // x-prefetch depth
#define NSS     (T_STEPS / SS)

// 2*log2(e): folded into all weights/biases so tanh needs no input scaling
#define KSC 2.885390081777927f

typedef _Float16 h2 __attribute__((ext_vector_type(2)));
typedef _Float16 h4 __attribute__((ext_vector_type(4)));
typedef _Float16 h8 __attribute__((ext_vector_type(8)));
typedef float    f4 __attribute__((ext_vector_type(4)));

#define MFMA(a, b, c) __builtin_amdgcn_mfma_f32_16x16x32_f16((a), (b), (c), 0, 0, 0)

union F8  { h8 v; h2 p[4]; };
union H4U { h4 v; h2 p[2]; };
union H8Q { h8 v; h4 h[2]; };

__device__ __forceinline__ h2 pkrtz(float a, float b) {
    return __builtin_bit_cast(h2, __builtin_amdgcn_cvt_pkrtz(a, b));
}

// tanh(a) where input kx = KSC*a (pre-scaled via weights):
// 4 instrs/elem (exp2, add, rcp, fma); saturates correctly at +/-inf.
__device__ __forceinline__ float tanh_pre(float kx) {
    float e = __builtin_amdgcn_exp2f(kx);
    return 1.0f - 2.0f * __builtin_amdgcn_rcpf(e + 1.0f);
}

// fragment load with fold-in scale (runs once at init; cost irrelevant)
__device__ __forceinline__ h8 load_frag_f16_s(const float* Wrow, float s) {
    const float4* p = (const float4*)Wrow;
    float4 a = p[0], b = p[1];
    F8 f; f.p[0] = pkrtz(s * a.x, s * a.y); f.p[1] = pkrtz(s * a.z, s * a.w);
          f.p[2] = pkrtz(s * b.x, s * b.y); f.p[3] = pkrtz(s * b.z, s * b.w);
    return f.v;
}

// Barrier draining ONLY lgkmcnt (LDS); x-prefetch globals stay in flight.
// lgkmcnt(0) also retires this step's stable-buffer reads before any wave
// can cross and overwrite them next step (double-buffer race-safety).
#define LDS_BARRIER() asm volatile("s_waitcnt lgkmcnt(0)\n\ts_barrier" ::: "memory")

// Sigma quarter-split (derived from R2/R9's sigma): wave owns ONE m-tile mt;
// its 4 post-tanh C values pack to an h4 = half of the k-tile (mt>>1)
// B-fragment, at the SAME lane. Full B-frag kt = concat(X[2kt], X[2kt+1])
// at this lane -> 2x ds_read_b64 (read2-able, 512B apart). Exchange layout
// [bf][mt][lane] h4: 8B/lane linear, conflict-free class (R5-measured).
// HW model (R10-R12 fit): lone-wave issue ~6cy/instr; 2 waves/SIMD fill
// slots. This halves per-wave tanh work (16 instr) vs R12's half-split (32).
__global__ __launch_bounds__(512, 1)
void rnn2_q8(const float* __restrict__ x,
             const float* __restrict__ Wih0, const float* __restrict__ Whh0,
             const float* __restrict__ bih0, const float* __restrict__ bhh0,
             const float* __restrict__ Wih1, const float* __restrict__ Whh1,
             const float* __restrict__ bih1, const float* __restrict__ bhh1,
             const float* __restrict__ fcw,  const float* __restrict__ fcb,
             float* __restrict__ out) {
    const int tid  = threadIdx.x;
    const int w    = tid >> 6;     // 0-3: L0 quarter mt; 4-7: L1 quarter mt
    const int mt   = w & 3;        // owned m-tile (sigma rows)
    const bool isL0 = (w < 4);     // SIMD k hosts waves k, k+4: L0+L1 pair
    const int lane = tid & 63;
    const int n    = lane & 15;    // seq column / A-row-slot
    const int q    = lane >> 4;
    const int bseq = blockIdx.x * SPW;

    // [bf][mt][lane] h4 quarters; full frag kt = h[2kt],h[2kt+1]. 4KB+4KB.
    __shared__ __align__(16) h4 X0[2][4][64];
    __shared__ __align__(16) h4 X1[2][4][64];
    __shared__ float red[4][SPW];

    // zero-init: H0(-1)=H1(-1)=0 reads at t=0/1 come from these
    { h4 z = {}; X0[w >> 2][mt][lane] = z; X1[w >> 2][mt][lane] = z; }
    __syncthreads();

    const h2 z2 = pkrtz(0.f, 0.f);
    const float fcb0 = fcb[0];
    // sigma A-row for this wave's A fragments (A row-slot = n)
    const int ar = 32 * (mt >> 1) + 4 * (mt & 1) + 8 * (n >> 2) + (n & 3);

    if (isL0) {
        // ---------------- layer-0 quarter-wave ----------------
        h8 wh[2], wi;              // KSC-scaled
        f4 bias;
        #pragma unroll
        for (int kt = 0; kt < 2; ++kt)
            wh[kt] = load_frag_f16_s(Whh0 + ar * HID + 32 * kt + 8 * q, KSC);
        {
            const float2 ww = *(const float2*)(Wih0 + ar * IN0 + 2 * q);
            F8 f; f.p[0] = pkrtz(KSC * ww.x, KSC * ww.y);
            f.p[1] = z2; f.p[2] = z2; f.p[3] = z2;
            wi = f.v;
        }
        #pragma unroll
        for (int r = 0; r < 4; ++r) {
            const int cr = 32 * (mt >> 1) + 4 * (mt & 1) + 8 * q + r;
            bias[r] = KSC * (bih0[cr] + bhh0[cr]);
        }
        const float* xrow = x + ((size_t)(bseq + n)) * T_STEPS * IN0 + 2 * q;
        float2 xb[SS];             // xb[t&7] = x(t) at top of step t
        #pragma unroll
        for (int i = 0; i < SS; ++i)
            xb[i] = *(const float2*)(xrow + i * IN0);

        for (int s = 0; s < NSS; ++s) {
            #pragma unroll
            for (int i = 0; i < SS; ++i) {
                const int t = SS * s + i;
                const int bf = t & 1;
                // (1) chain reads FIRST: both H0(t-1) fragments (4x h4)
                H8Q f0, f1;
                f0.h[0] = X0[bf ^ 1][0][lane]; f0.h[1] = X0[bf ^ 1][1][lane];
                f1.h[0] = X0[bf ^ 1][2][lane]; f1.h[1] = X0[bf ^ 1][3][lane];
                // (2) read shadow: cp = bias + Wih@x(t) (pure register)
                F8 xf; xf.p[0] = pkrtz(xb[i].x, xb[i].y);
                xf.p[1] = z2; xf.p[2] = z2; xf.p[3] = z2;
                f4 cp = MFMA(wi, xf.v, bias);
                int tn = t + SS; if (tn > T_STEPS - 1) tn = T_STEPS - 1;
                xb[i] = *(const float2*)(xrow + tn * IN0);
                // (3) chain: 2 MFMA, 4-elem tanh, pack, publish
                f4 c = MFMA(wh[0], f0.v, cp);
                c    = MFMA(wh[1], f1.v, c);
                H4U u;
                u.p[0] = pkrtz(tanh_pre(c[0]), tanh_pre(c[1]));
                u.p[1] = pkrtz(tanh_pre(c[2]), tanh_pre(c[3]));
                X0[bf][mt][lane] = u.v;
                LDS_BARRIER();
            }
        }
    } else {
        // ---------------- layer-1 quarter-wave ----------------
        // step t computes H1(t-1); ALL inputs are stable bf^1 buffers.
        h8 wa[2], wb[2];           // KSC-scaled
        f4 bias, fcv;
        #pragma unroll
        for (int kt = 0; kt < 2; ++kt) {
            wa[kt] = load_frag_f16_s(Wih1 + ar * HID + 32 * kt + 8 * q, KSC);
            wb[kt] = load_frag_f16_s(Whh1 + ar * HID + 32 * kt + 8 * q, KSC);
        }
        #pragma unroll
        for (int r = 0; r < 4; ++r) {
            const int cr = 32 * (mt >> 1) + 4 * (mt & 1) + 8 * q + r;
            bias[r] = KSC * (bih1[cr] + bhh1[cr]);
            fcv[r]  = fcw[cr];     // unscaled: applied post-tanh
        }
        for (int s = 0; s < NSS; ++s) {
            #pragma unroll
            for (int i = 0; i < SS; ++i) {
                const int t = SS * s + i;
                const int bf = t & 1;
                // chain reads: H0(t-1) and H1(t-2) fragments (8x h4)
                H8Q g0, g1, k0, k1;
                g0.h[0] = X0[bf ^ 1][0][lane]; g0.h[1] = X0[bf ^ 1][1][lane];
                g1.h[0] = X0[bf ^ 1][2][lane]; g1.h[1] = X0[bf ^ 1][3][lane];
                k0.h[0] = X1[bf ^ 1][0][lane]; k0.h[1] = X1[bf ^ 1][1][lane];
                k1.h[0] = X1[bf ^ 1][2][lane]; k1.h[1] = X1[bf ^ 1][3][lane];
                // fully-chained accumulate (bias rides the first MFMA)
                f4 e = MFMA(wa[0], g0.v, bias);
                e    = MFMA(wa[1], g1.v, e);
                e    = MFMA(wb[0], k0.v, e);
                e    = MFMA(wb[1], k1.v, e);
                H4U u;
                u.p[0] = pkrtz(tanh_pre(e[0]), tanh_pre(e[1]));
                u.p[1] = pkrtz(tanh_pre(e[2]), tanh_pre(e[3]));
                // t==0 computes H1(-1) which must stay 0: skip the write
                // (uniform branch, exists only in the i==0 unroll body)
                if (i == 0) {
                    if (s != 0) X1[bf][mt][lane] = u.v;
                } else {
                    X1[bf][mt][lane] = u.v;
                }
                LDS_BARRIER();
            }
        }
        // epilogue: H1(511) from H0(511)=X0[1], H1(510)=X1[1]
        {
            H8Q g0, g1, k0, k1;
            g0.h[0] = X0[1][0][lane]; g0.h[1] = X0[1][1][lane];
            g1.h[0] = X0[1][2][lane]; g1.h[1] = X0[1][3][lane];
            k0.h[0] = X1[1][0][lane]; k0.h[1] = X1[1][1][lane];
            k1.h[0] = X1[1][2][lane]; k1.h[1] = X1[1][3][lane];
            f4 e = MFMA(wa[0], g0.v, bias);
            e    = MFMA(wa[1], g1.v, e);
            e    = MFMA(wb[0], k0.v, e);
            e    = MFMA(wb[1], k1.v, e);
            float sacc = 0.f;
            #pragma unroll
            for (int r = 0; r < 4; ++r) sacc += fcv[r] * tanh_pre(e[r]);
            sacc += __shfl_xor(sacc, 16, 64);
            sacc += __shfl_xor(sacc, 32, 64);
            if (lane < 16) red[mt][n] = sacc;   // q==0 lanes
        }
    }

    __syncthreads();
    if (tid < SPW)
        out[bseq + tid] = red[0][tid] + red[1][tid] + red[2][tid] + red[3][tid] + fcb0;
}

extern "C" void kernel_launch(void* const* d_in, const int* in_sizes, int n_in,
                              void* d_out, int out_size, void* d_ws, size_t ws_size,
                              hipStream_t stream) {
    const float* x    = (const float*)d_in[0];
    const float* Wih0 = (const float*)d_in[1];
    const float* Whh0 = (const float*)d_in[2];
    const float* bih0 = (const float*)d_in[3];
    const float* bhh0 = (const float*)d_in[4];
    const float* Wih1 = (const float*)d_in[5];
    const float* Whh1 = (const float*)d_in[6];
    const float* bih1 = (const float*)d_in[7];
    const float* bhh1 = (const float*)d_in[8];
    const float* fcw  = (const float*)d_in[9];
    const float* fcb  = (const float*)d_in[10];
    float* out = (float*)d_out;

    rnn2_q8<<<dim3(NBLK), dim3(512), 0, stream>>>(
        x, Wih0, Whh0, bih0, bhh0, Wih1, Whh1, bih1, bhh1, fcw, fcb, out);
}